// Round 7
// baseline (1257.702 us; speedup 1.0000x reference)
//
#include <hip/hip_runtime.h>
#include <hip/hip_cooperative_groups.h>
#include <stdint.h>

namespace cg = cooperative_groups;

// Problem dims
#define MROWS 32768   // B*T
#define TSEQ  1024
#define BBATCH 32
#define INDIM 1536
#define DDIM  768
#define NCAT  2304    // un_emb (768) + pw_x (768) + pw_y (768)

typedef short short8 __attribute__((ext_vector_type(8)));
typedef short short4v __attribute__((ext_vector_type(4)));
typedef float f32x4  __attribute__((ext_vector_type(4)));

__device__ __forceinline__ float b2f(ushort u) {
    union { uint32_t u; float f; } x; x.u = ((uint32_t)u) << 16; return x.f;
}
__device__ __forceinline__ ushort f2b(float f) {
    union { float f; uint32_t u; } x; x.f = f;
    uint32_t r = x.u + 0x7fffu + ((x.u >> 16) & 1u);
    return (ushort)(r >> 16);
}

__device__ __forceinline__ void cvt4(const float* __restrict__ in, ushort* __restrict__ out, int i) {
    float4 v = ((const float4*)in)[i];
    ushort4 o;
    o.x = f2b(v.x); o.y = f2b(v.y); o.z = f2b(v.z); o.w = f2b(v.w);
    ((ushort4*)out)[i] = o;
}

// ---------------- ALL conversions + bias concat + accumulator zeroing, ONE launch ----------------
// float4-index ranges (see kernel_launch for layout):
#define C0 12582912   // x -> X16
#define C1 13172736   // fc1_w -> W1
#define C2 13467648   // fc2_w -> W2
#define C3 13615104   // un_emb_w -> W3[0]
#define C4 13762560   // pw_x_w -> W3[1]
#define C5 13910016   // pw_y_w -> W3[2]
#define C6 13910592   // biases -> B3
#define C7 13916736   // zero YBAR
#define C8 13922880   // zero d_out
#define C9 13947456   // zero SE/SX/SY (contiguous)
__global__ void cvt_all(const float* __restrict__ x,
                        const float* __restrict__ fc1_w, const float* __restrict__ fc2_w,
                        const float* __restrict__ w3a, const float* __restrict__ w3b,
                        const float* __restrict__ w3c,
                        const float* __restrict__ ba, const float* __restrict__ bb,
                        const float* __restrict__ bc,
                        ushort* __restrict__ X16, ushort* __restrict__ W1,
                        ushort* __restrict__ W2, ushort* __restrict__ W3,
                        float* __restrict__ B3, float* __restrict__ ybar_z,
                        float* __restrict__ out_z, float* __restrict__ stats_z)
{
    int i = blockIdx.x * 256 + threadIdx.x;  // float4 index
    float4 z = {0.f, 0.f, 0.f, 0.f};
    if (i < C0)       cvt4(x, X16, i);
    else if (i < C1)  cvt4(fc1_w, W1, i - C0);
    else if (i < C2)  cvt4(fc2_w, W2, i - C1);
    else if (i < C3)  cvt4(w3a, W3,           i - C2);
    else if (i < C4)  cvt4(w3b, W3 + 589824,  i - C3);
    else if (i < C5)  cvt4(w3c, W3 + 1179648, i - C4);
    else if (i < C6) {
        int j = i - C5;  // 0..575 float4s of B3 (2304 floats)
        const float* src = (j < 192) ? ba : (j < 384) ? bb : bc;
        int off = (j < 192) ? j : (j < 384) ? (j - 192) : (j - 384);
        ((float4*)B3)[j] = ((const float4*)src)[off];
    }
    else if (i < C7)  ((float4*)ybar_z)[i - C6] = z;
    else if (i < C8)  ((float4*)out_z)[i - C7] = z;
    else if (i < C9)  ((float4*)stats_z)[i - C8] = z;
}

// ---------------- bf16 GEMM: C[M,N] = A[M,K] * B[N,K]^T + bias, optional relu on cols < relu_ncols
// 128x128 tile / block, 4 waves (2x2), each wave 64x64 = 4x4 MFMA 16x16x32 subtiles.
// BK=64 (R5: GEMM1 217->177us, MfmaUtil 39%). Staging XOR-swizzle: coalesced 64B
// per 4 lanes AND conflict-free ds_read_b128 (R4/R5: SQ_LDS_BANK_CONFLICT=0).
// XCD-pinned block swizzle keeps all ntiles consumers of an A-tile on one XCD.
//
// Optional fused row-stats (GEMM3): if urw != nullptr, each block also reduces its
// tile's per-row contribution to SE (sum e*urw), SX (sum xe^2), SY (sum ye^2) and
// atomicAdds them (~256 atomics/block, epilogue-only). Tiles never straddle the
// three 768-wide sections since 768%128==0.
// Requires (M/128)%8==0, N%128==0, K%64==0.
__global__ __launch_bounds__(256, 2)
void gemm_bt(const ushort* __restrict__ A, const ushort* __restrict__ Bm,
             const float* __restrict__ bias, ushort* __restrict__ C,
             int M, int N, int K, int relu_ncols,
             const float* __restrict__ urw, float* __restrict__ SE,
             float* __restrict__ SX, float* __restrict__ SY)
{
    __shared__ __align__(16) ushort lA[128 * 64];  // 16 KB, 16 segments of 16x32
    __shared__ __align__(16) ushort lB[128 * 64];  // 16 KB

    const int tid  = threadIdx.x;
    const int lane = tid & 63, wave = tid >> 6;
    const int wm = wave & 1, wn = wave >> 1;       // 2x2 wave grid
    const int quad = lane >> 4, r16 = lane & 15;

    // XCD-pinned block swizzle
    const int ntiles = N >> 7;
    const int xcd = blockIdx.x & 7;
    const int j   = blockIdx.x >> 3;
    const int g   = j / ntiles;            // m-group within this XCD
    const int n_t = j - g * ntiles;
    const int m_t = xcd + (g << 3);
    const int m0 = m_t * 128, n0 = n_t * 128;

    // staging lane->global map: row = lane>>2, kb = (lane&3)^((lane>>3)&3)
    const int srow = lane >> 2;
    const int scol = ((lane & 3) ^ ((lane >> 3) & 3)) * 8;
    // fragment-read granule offset (ushorts): (r*4 + (q ^ ((r>>1)&3))) * 8
    const int goff = (r16 << 5) + ((quad ^ ((r16 >> 1) & 3)) << 3);

    f32x4 acc[4][4] = {};

    const int kIters = K >> 6;
    for (int kt = 0; kt < kIters; ++kt) {
        const int k0 = kt << 6;
        __syncthreads();   // previous round's LDS reads complete
#pragma unroll
        for (int c = 0; c < 4; ++c) {
            int S  = wave * 4 + c;
            int kh = S >> 3, rs = S & 7;
            int row = rs * 16 + srow;
            int kc  = k0 + kh * 32 + scol;
            const ushort* ga = A + (size_t)(m0 + row) * K + kc;
            __builtin_amdgcn_global_load_lds(
                (const __attribute__((address_space(1))) void*)ga,
                (__attribute__((address_space(3))) void*)&lA[S * 512], 16, 0, 0);
            const ushort* gb = Bm + (size_t)(n0 + row) * K + kc;
            __builtin_amdgcn_global_load_lds(
                (const __attribute__((address_space(1))) void*)gb,
                (__attribute__((address_space(3))) void*)&lB[S * 512], 16, 0, 0);
        }
        __syncthreads();   // staging complete

#pragma unroll
        for (int kh = 0; kh < 2; ++kh) {
            short8 af[4], bf[4];
#pragma unroll
            for (int i = 0; i < 4; ++i)
                af[i] = *(const short8*)&lA[kh * 4096 + (wm * 4 + i) * 512 + goff];
#pragma unroll
            for (int j2 = 0; j2 < 4; ++j2)
                bf[j2] = *(const short8*)&lB[kh * 4096 + (wn * 4 + j2) * 512 + goff];
#pragma unroll
            for (int i = 0; i < 4; ++i)
#pragma unroll
                for (int j2 = 0; j2 < 4; ++j2)
                    acc[i][j2] = __builtin_amdgcn_mfma_f32_16x16x32_bf16(af[i], bf[j2], acc[i][j2], 0, 0, 0);
        }
    }

    // epilogue: C/D layout col = lane&15, row = quad*4 + reg  [m89-verified]
    const bool stats = (urw != nullptr);
    const int sec = n0 / DDIM;           // 0=e, 1=xe, 2=ye (GEMM3 only)
    float st[4][4] = {};                 // per-(i,rr) row partials
#pragma unroll
    for (int j2 = 0; j2 < 4; ++j2) {
        int gn = n0 + wn * 64 + j2 * 16 + r16;
        float bv = bias[gn];
        bool dorelu = gn < relu_ncols;
        float uw = (stats && sec == 0) ? urw[gn] : 0.f;
#pragma unroll
        for (int i = 0; i < 4; ++i) {
            int gmb = m0 + wm * 64 + i * 16 + quad * 4;
#pragma unroll
            for (int rr = 0; rr < 4; ++rr) {
                float v = acc[i][j2][rr] + bv;
                if (dorelu) v = fmaxf(v, 0.f);
                C[(size_t)(gmb + rr) * N + gn] = f2b(v);
                if (stats) st[i][rr] += (sec == 0) ? v * uw : v * v;
            }
        }
    }
    if (stats) {
        // reduce each st over the 16 lanes of r16 (butterfly within 16-lane groups)
#pragma unroll
        for (int i = 0; i < 4; ++i)
#pragma unroll
            for (int rr = 0; rr < 4; ++rr) {
                float v = st[i][rr];
                v += __shfl_xor(v, 1, 64);
                v += __shfl_xor(v, 2, 64);
                v += __shfl_xor(v, 4, 64);
                v += __shfl_xor(v, 8, 64);
                st[i][rr] = v;
            }
        if (r16 == 0) {
            float* dst = (sec == 0) ? SE : (sec == 1) ? SX : SY;
#pragma unroll
            for (int i = 0; i < 4; ++i)
#pragma unroll
                for (int rr = 0; rr < 4; ++rr)
                    atomicAdd(&dst[m0 + wm * 64 + i * 16 + quad * 4 + rr], st[i][rr]);
        }
    }
}

// ---------------- fused tail (cooperative, 1024 blocks x 256 thr, 4 blocks/CU) ----------------
// P1 ybar  : ybar[b,d] = (1/T) sum_s ye[b,s,d]/max(||ye[b,s]||,eps)   (atomics, YBAR pre-zeroed)
// P2 scores: scores[m] = rw0*(SE[m]+urb) + rw1*dot(xe[m],ybar[b])/max(sqrt(SX[m]),eps)
// P3 softmax over T per batch (blocks 0..31)
// P4 out   : out[b,d] = sum_t wsm[b,t]*u[b,t,d]   (atomics, d_out pre-zeroed)
__global__ __launch_bounds__(256, 4)
void tail_coop(const ushort* __restrict__ G3, const ushort* __restrict__ U16,
               const float* __restrict__ SE, const float* __restrict__ SX,
               const float* __restrict__ SY, const float* __restrict__ urb,
               const float* __restrict__ red_w, float* __restrict__ ybar,
               float* __restrict__ scores, float* __restrict__ wsm,
               float* __restrict__ out)
{
    cg::grid_group grid = cg::this_grid();
    const int tid = threadIdx.x;
    const int lane = tid & 63, wv = tid >> 6;
    __shared__ float smem[64];

    // ---- P1: ybar partials (block = (batch<<5) | chunk) ----
    {
        int b = blockIdx.x >> 5, s0 = (blockIdx.x & 31) * 32;
        if (tid < 32) {
            float v = SY[b * TSEQ + s0 + tid];
            smem[tid] = (1.0f / TSEQ) / fmaxf(sqrtf(v), 1e-12f);
        }
        __syncthreads();
        float a0 = 0.f, a1 = 0.f, a2 = 0.f;
#pragma unroll 8
        for (int s = 0; s < 32; ++s) {
            const ushort* row = G3 + (size_t)(b * TSEQ + s0 + s) * NCAT + 2 * DDIM;
            float w = smem[s];
            a0 += b2f(row[tid])       * w;
            a1 += b2f(row[tid + 256]) * w;
            a2 += b2f(row[tid + 512]) * w;
        }
        atomicAdd(&ybar[b * DDIM + tid],       a0);
        atomicAdd(&ybar[b * DDIM + tid + 256], a1);
        atomicAdd(&ybar[b * DDIM + tid + 512], a2);
    }
    __threadfence();
    grid.sync();

    // ---- P2: scores, 32 rows/block, one row per wave iteration ----
    {
        for (int k = 0; k < 8; ++k) {
            int m = blockIdx.x * 32 + wv * 8 + k;
            int b = m >> 10;
            // lane covers ushort4 chunks lane, lane+64, lane+128 of xe's 192 chunks
            const ushort* xe = G3 + (size_t)m * NCAT + DDIM;
            const float4* yb = (const float4*)(ybar + b * DDIM);
            float s = 0.f;
#pragma unroll
            for (int c0 = 0; c0 < 3; ++c0) {
                int c = lane + c0 * 64;
                short4v v = *(const short4v*)(xe + c * 4);
                float4 yv = yb[c];
                s += b2f((ushort)v[0]) * yv.x + b2f((ushort)v[1]) * yv.y
                   + b2f((ushort)v[2]) * yv.z + b2f((ushort)v[3]) * yv.w;
            }
#pragma unroll
            for (int off = 32; off; off >>= 1) s += __shfl_xor(s, off, 64);
            if (lane == 0) {
                float rnx = 1.f / fmaxf(sqrtf(SX[m]), 1e-12f);
                scores[m] = red_w[0] * (SE[m] + urb[0]) + red_w[1] * (rnx * s);
            }
        }
    }
    __threadfence();
    grid.sync();

    // ---- P3: softmax per batch (blocks 0..31) ----
    if (blockIdx.x < BBATCH) {
        int b = blockIdx.x;
        float v[4];
        float lm = -1e30f;
#pragma unroll
        for (int i = 0; i < 4; ++i) {
            v[i] = scores[b * TSEQ + i * 256 + tid];
            lm = fmaxf(lm, v[i]);
        }
        for (int off = 32; off; off >>= 1) lm = fmaxf(lm, __shfl_down(lm, off, 64));
        if (lane == 0) smem[wv] = lm;
        __syncthreads();
        float smax = fmaxf(fmaxf(smem[0], smem[1]), fmaxf(smem[2], smem[3]));
        float e[4];
        float ls = 0.f;
#pragma unroll
        for (int i = 0; i < 4; ++i) { e[i] = expf(v[i] - smax); ls += e[i]; }
        for (int off = 32; off; off >>= 1) ls += __shfl_down(ls, off, 64);
        __syncthreads();
        if (lane == 0) smem[8 + wv] = ls;
        __syncthreads();
        float inv = 1.f / (smem[8] + smem[9] + smem[10] + smem[11]);
#pragma unroll
        for (int i = 0; i < 4; ++i) wsm[b * TSEQ + i * 256 + tid] = e[i] * inv;
    }
    __threadfence();
    grid.sync();

    // ---- P4: weighted output sum ----
    {
        int b = blockIdx.x >> 5, t0 = (blockIdx.x & 31) * 32;
        __syncthreads();
        if (tid < 32) smem[tid] = wsm[b * TSEQ + t0 + tid];
        __syncthreads();
        float a0 = 0.f, a1 = 0.f, a2 = 0.f;
#pragma unroll 8
        for (int t = 0; t < 32; ++t) {
            const ushort* row = U16 + (size_t)(b * TSEQ + t0 + t) * DDIM;
            float w = smem[t];
            a0 += b2f(row[tid])       * w;
            a1 += b2f(row[tid + 256]) * w;
            a2 += b2f(row[tid + 512]) * w;
        }
        atomicAdd(&out[b * DDIM + tid],       a0);
        atomicAdd(&out[b * DDIM + tid + 256], a1);
        atomicAdd(&out[b * DDIM + tid + 512], a2);
    }
}

// ---------------- workspace layout (bytes) ----------------
// G3 (e|xe|ye bf16, 151 MB) aliases the X16+H16 region (dead after GEMM2).
static const size_t O_X16   = 0;            // 32768*1536*2 = 100663296
static const size_t O_H16   = 100663296;    // 100663296
static const size_t O_G3    = 0;            // 150994944 (alias)
static const size_t O_U16   = 201326592;    // 50331648
static const size_t O_W1    = 251658240;    // 4718592
static const size_t O_W2    = 256376832;    // 2359296
static const size_t O_W3    = 258736128;    // 3538944
static const size_t O_B3    = 262275072;    // 9216
static const size_t O_SE    = 262284288;    // 131072  (SE/SX/SY contiguous)
static const size_t O_SX    = 262415360;    // 131072
static const size_t O_SY    = 262546432;    // 131072
static const size_t O_SCORE = 262677504;    // 131072
static const size_t O_WSM   = 262808576;    // 131072
static const size_t O_YBAR  = 262939648;    // 98304
// total: 263037952 bytes (~263 MB)

extern "C" void kernel_launch(void* const* d_in, const int* in_sizes, int n_in,
                              void* d_out, int out_size, void* d_ws, size_t ws_size,
                              hipStream_t stream)
{
    const float* x        = (const float*)d_in[0];
    const float* fc1_w    = (const float*)d_in[1];
    const float* fc1_b    = (const float*)d_in[2];
    const float* fc2_w    = (const float*)d_in[3];
    const float* fc2_b    = (const float*)d_in[4];
    const float* un_emb_w = (const float*)d_in[5];
    const float* un_emb_b = (const float*)d_in[6];
    const float* un_red_w = (const float*)d_in[7];
    const float* un_red_b = (const float*)d_in[8];
    const float* pw_x_w   = (const float*)d_in[9];
    const float* pw_x_b   = (const float*)d_in[10];
    const float* pw_y_w   = (const float*)d_in[11];
    const float* pw_y_b   = (const float*)d_in[12];
    const float* red_w    = (const float*)d_in[13];

    char* ws = (char*)d_ws;
    ushort* X16 = (ushort*)(ws + O_X16);
    ushort* H16 = (ushort*)(ws + O_H16);
    ushort* G3  = (ushort*)(ws + O_G3);
    ushort* U16 = (ushort*)(ws + O_U16);
    ushort* W1  = (ushort*)(ws + O_W1);
    ushort* W2  = (ushort*)(ws + O_W2);
    ushort* W3  = (ushort*)(ws + O_W3);
    float*  B3  = (float*)(ws + O_B3);
    float*  SE  = (float*)(ws + O_SE);
    float*  SX  = (float*)(ws + O_SX);
    float*  SY  = (float*)(ws + O_SY);
    float*  SCORES = (float*)(ws + O_SCORE);
    float*  WSM = (float*)(ws + O_WSM);
    float*  YBAR = (float*)(ws + O_YBAR);

    // --- one conversion/zeroing pass: 13947456 float4 elements ---
    cvt_all<<<54483, 256, 0, stream>>>(x, fc1_w, fc2_w, un_emb_w, pw_x_w, pw_y_w,
                                       un_emb_b, pw_x_b, pw_y_b,
                                       X16, W1, W2, W3, B3, YBAR, (float*)d_out, SE);

    // --- GEMM chain (1-D grid, XCD-pinned swizzle inside kernel) ---
    // h = relu(x @ fc1_w^T + fc1_b)            [M,1536]
    gemm_bt<<<(MROWS / 128) * (INDIM / 128), 256, 0, stream>>>(
        X16, W1, fc1_b, H16, MROWS, INDIM, INDIM, INDIM,
        nullptr, nullptr, nullptr, nullptr);
    // u = h @ fc2_w^T + fc2_b                  [M,768]
    gemm_bt<<<(MROWS / 128) * (DDIM / 128), 256, 0, stream>>>(
        H16, W2, fc2_b, U16, MROWS, DDIM, INDIM, 0,
        nullptr, nullptr, nullptr, nullptr);
    // [e|xe|ye] = u @ [un_emb|pw_x|pw_y]^T + b  [M,2304], relu on e; fused row-stats
    gemm_bt<<<(MROWS / 128) * (NCAT / 128), 256, 0, stream>>>(
        U16, W3, B3, G3, MROWS, NCAT, DDIM, DDIM,
        un_red_w, SE, SX, SY);

    // --- fused cooperative tail: ybar -> scores -> softmax -> out ---
    void* args[] = { (void*)&G3, (void*)&U16, (void*)&SE, (void*)&SX, (void*)&SY,
                     (void*)&un_red_b, (void*)&red_w, (void*)&YBAR, (void*)&SCORES,
                     (void*)&WSM, (void*)&d_out };
    hipLaunchCooperativeKernel((void*)tail_coop, dim3(1024), dim3(256), args, 0, stream);
}

// Round 8
// 717.778 us; speedup vs baseline: 1.7522x; 1.7522x over previous
//
#include <hip/hip_runtime.h>
#include <stdint.h>

// Problem dims
#define MROWS 32768   // B*T
#define TSEQ  1024
#define BBATCH 32
#define INDIM 1536
#define DDIM  768
#define NCAT  2304    // un_emb (768) + pw_x (768) + pw_y (768)

typedef short short8 __attribute__((ext_vector_type(8)));
typedef short short4v __attribute__((ext_vector_type(4)));
typedef float f32x4  __attribute__((ext_vector_type(4)));

__device__ __forceinline__ float b2f(ushort u) {
    union { uint32_t u; float f; } x; x.u = ((uint32_t)u) << 16; return x.f;
}
__device__ __forceinline__ ushort f2b(float f) {
    union { float f; uint32_t u; } x; x.f = f;
    uint32_t r = x.u + 0x7fffu + ((x.u >> 16) & 1u);
    return (ushort)(r >> 16);
}

__device__ __forceinline__ void cvt4(const float* __restrict__ in, ushort* __restrict__ out, int i) {
    float4 v = ((const float4*)in)[i];
    ushort4 o;
    o.x = f2b(v.x); o.y = f2b(v.y); o.z = f2b(v.z); o.w = f2b(v.w);
    ((ushort4*)out)[i] = o;
}

// ---------------- ALL conversions + bias concat + accumulator zeroing, ONE launch ----------------
#define C0 12582912   // x -> X16
#define C1 13172736   // fc1_w -> W1
#define C2 13467648   // fc2_w -> W2
#define C3 13615104   // un_emb_w -> W3[0]
#define C4 13762560   // pw_x_w -> W3[1]
#define C5 13910016   // pw_y_w -> W3[2]
#define C6 13910592   // biases -> B3
#define C7 13916736   // zero YBAR
#define C8 13922880   // zero d_out
#define C9 13947456   // zero SE/SX/SY (contiguous)
__global__ void cvt_all(const float* __restrict__ x,
                        const float* __restrict__ fc1_w, const float* __restrict__ fc2_w,
                        const float* __restrict__ w3a, const float* __restrict__ w3b,
                        const float* __restrict__ w3c,
                        const float* __restrict__ ba, const float* __restrict__ bb,
                        const float* __restrict__ bc,
                        ushort* __restrict__ X16, ushort* __restrict__ W1,
                        ushort* __restrict__ W2, ushort* __restrict__ W3,
                        float* __restrict__ B3, float* __restrict__ ybar_z,
                        float* __restrict__ out_z, float* __restrict__ stats_z)
{
    int i = blockIdx.x * 256 + threadIdx.x;  // float4 index
    float4 z = {0.f, 0.f, 0.f, 0.f};
    if (i < C0)       cvt4(x, X16, i);
    else if (i < C1)  cvt4(fc1_w, W1, i - C0);
    else if (i < C2)  cvt4(fc2_w, W2, i - C1);
    else if (i < C3)  cvt4(w3a, W3,           i - C2);
    else if (i < C4)  cvt4(w3b, W3 + 589824,  i - C3);
    else if (i < C5)  cvt4(w3c, W3 + 1179648, i - C4);
    else if (i < C6) {
        int j = i - C5;  // 0..575 float4s of B3 (2304 floats)
        const float* src = (j < 192) ? ba : (j < 384) ? bb : bc;
        int off = (j < 192) ? j : (j < 384) ? (j - 192) : (j - 384);
        ((float4*)B3)[j] = ((const float4*)src)[off];
    }
    else if (i < C7)  ((float4*)ybar_z)[i - C6] = z;
    else if (i < C8)  ((float4*)out_z)[i - C7] = z;
    else if (i < C9)  ((float4*)stats_z)[i - C8] = z;
}

// ---------------- bf16 GEMM: C[M,N] = A[M,K] * B[N,K]^T + bias, optional relu on cols < relu_ncols
// 128x128 tile / block, 4 waves (2x2), each wave 64x64 = 4x4 MFMA 16x16x32 subtiles.
// BK=64 (R5: GEMM1 217->177us, MfmaUtil 39%). Staging XOR-swizzle: coalesced 64B
// per 4 lanes AND conflict-free ds_read_b128 (R4/R5: SQ_LDS_BANK_CONFLICT=0).
// XCD-pinned block swizzle keeps all ntiles consumers of an A-tile on one XCD.
// Optional fused row-stats (GEMM3, R7-verified): per-row SE/SX/SY atomics in epilogue.
// Requires (M/128)%8==0, N%128==0, K%64==0.
__global__ __launch_bounds__(256, 2)
void gemm_bt(const ushort* __restrict__ A, const ushort* __restrict__ Bm,
             const float* __restrict__ bias, ushort* __restrict__ C,
             int M, int N, int K, int relu_ncols,
             const float* __restrict__ urw, float* __restrict__ SE,
             float* __restrict__ SX, float* __restrict__ SY)
{
    __shared__ __align__(16) ushort lA[128 * 64];  // 16 KB, 16 segments of 16x32
    __shared__ __align__(16) ushort lB[128 * 64];  // 16 KB

    const int tid  = threadIdx.x;
    const int lane = tid & 63, wave = tid >> 6;
    const int wm = wave & 1, wn = wave >> 1;       // 2x2 wave grid
    const int quad = lane >> 4, r16 = lane & 15;

    // XCD-pinned block swizzle
    const int ntiles = N >> 7;
    const int xcd = blockIdx.x & 7;
    const int j   = blockIdx.x >> 3;
    const int g   = j / ntiles;            // m-group within this XCD
    const int n_t = j - g * ntiles;
    const int m_t = xcd + (g << 3);
    const int m0 = m_t * 128, n0 = n_t * 128;

    // staging lane->global map: row = lane>>2, kb = (lane&3)^((lane>>3)&3)
    const int srow = lane >> 2;
    const int scol = ((lane & 3) ^ ((lane >> 3) & 3)) * 8;
    // fragment-read granule offset (ushorts): (r*4 + (q ^ ((r>>1)&3))) * 8
    const int goff = (r16 << 5) + ((quad ^ ((r16 >> 1) & 3)) << 3);

    f32x4 acc[4][4] = {};

    const int kIters = K >> 6;
    for (int kt = 0; kt < kIters; ++kt) {
        const int k0 = kt << 6;
        __syncthreads();   // previous round's LDS reads complete
#pragma unroll
        for (int c = 0; c < 4; ++c) {
            int S  = wave * 4 + c;
            int kh = S >> 3, rs = S & 7;
            int row = rs * 16 + srow;
            int kc  = k0 + kh * 32 + scol;
            const ushort* ga = A + (size_t)(m0 + row) * K + kc;
            __builtin_amdgcn_global_load_lds(
                (const __attribute__((address_space(1))) void*)ga,
                (__attribute__((address_space(3))) void*)&lA[S * 512], 16, 0, 0);
            const ushort* gb = Bm + (size_t)(n0 + row) * K + kc;
            __builtin_amdgcn_global_load_lds(
                (const __attribute__((address_space(1))) void*)gb,
                (__attribute__((address_space(3))) void*)&lB[S * 512], 16, 0, 0);
        }
        __syncthreads();   // staging complete

#pragma unroll
        for (int kh = 0; kh < 2; ++kh) {
            short8 af[4], bf[4];
#pragma unroll
            for (int i = 0; i < 4; ++i)
                af[i] = *(const short8*)&lA[kh * 4096 + (wm * 4 + i) * 512 + goff];
#pragma unroll
            for (int j2 = 0; j2 < 4; ++j2)
                bf[j2] = *(const short8*)&lB[kh * 4096 + (wn * 4 + j2) * 512 + goff];
#pragma unroll
            for (int i = 0; i < 4; ++i)
#pragma unroll
                for (int j2 = 0; j2 < 4; ++j2)
                    acc[i][j2] = __builtin_amdgcn_mfma_f32_16x16x32_bf16(af[i], bf[j2], acc[i][j2], 0, 0, 0);
        }
    }

    // epilogue: C/D layout col = lane&15, row = quad*4 + reg  [m89-verified]
    const bool stats = (urw != nullptr);
    const int sec = n0 / DDIM;           // 0=e, 1=xe, 2=ye (GEMM3 only)
    float st[4][4] = {};                 // per-(i,rr) row partials
#pragma unroll
    for (int j2 = 0; j2 < 4; ++j2) {
        int gn = n0 + wn * 64 + j2 * 16 + r16;
        float bv = bias[gn];
        bool dorelu = gn < relu_ncols;
        float uw = (stats && sec == 0) ? urw[gn] : 0.f;
#pragma unroll
        for (int i = 0; i < 4; ++i) {
            int gmb = m0 + wm * 64 + i * 16 + quad * 4;
#pragma unroll
            for (int rr = 0; rr < 4; ++rr) {
                float v = acc[i][j2][rr] + bv;
                if (dorelu) v = fmaxf(v, 0.f);
                C[(size_t)(gmb + rr) * N + gn] = f2b(v);
                if (stats) st[i][rr] += (sec == 0) ? v * uw : v * v;
            }
        }
    }
    if (stats) {
#pragma unroll
        for (int i = 0; i < 4; ++i)
#pragma unroll
            for (int rr = 0; rr < 4; ++rr) {
                float v = st[i][rr];
                v += __shfl_xor(v, 1, 64);
                v += __shfl_xor(v, 2, 64);
                v += __shfl_xor(v, 4, 64);
                v += __shfl_xor(v, 8, 64);
                st[i][rr] = v;
            }
        if (r16 == 0) {
            float* dst = (sec == 0) ? SE : (sec == 1) ? SX : SY;
#pragma unroll
            for (int i = 0; i < 4; ++i)
#pragma unroll
                for (int rr = 0; rr < 4; ++rr)
                    atomicAdd(&dst[m0 + wm * 64 + i * 16 + quad * 4 + rr], st[i][rr]);
        }
    }
}

// ---------------- ybar[b,d] += partial over a 32-step s chunk ----------------
// ybar[b,d] = (1/T) * sum_s ye[b,s,d] / max(||ye[b,s]||,1e-12); grid (B, 32).
__global__ void ybar_k(const ushort* __restrict__ G3, const float* __restrict__ sy,
                       float* __restrict__ ybar)
{
    int b = blockIdx.x, s0 = blockIdx.y * 32;
    int tid = threadIdx.x;
    __shared__ float sr[32];
    if (tid < 32) {
        float v = sy[b * TSEQ + s0 + tid];
        sr[tid] = (1.0f / TSEQ) / fmaxf(sqrtf(v), 1e-12f);
    }
    __syncthreads();
    float a0 = 0.f, a1 = 0.f, a2 = 0.f;
#pragma unroll 8
    for (int s = 0; s < 32; ++s) {
        const ushort* row = G3 + (size_t)(b * TSEQ + s0 + s) * NCAT + 2 * DDIM;
        float w = sr[s];
        a0 += b2f(row[tid])       * w;
        a1 += b2f(row[tid + 256]) * w;
        a2 += b2f(row[tid + 512]) * w;
    }
    atomicAdd(&ybar[b * DDIM + tid],       a0);
    atomicAdd(&ybar[b * DDIM + tid + 256], a1);
    atomicAdd(&ybar[b * DDIM + tid + 512], a2);
}

// ---------------- scores: wave-per-row, 4 rows/block (8192 blocks) ----------------
// scores[m] = rw0*(SE[m]+urb) + rw1 * dot(xe[m],ybar[b]) / max(sqrt(SX[m]),1e-12)
__global__ void pw_scores_k(const ushort* __restrict__ G3, const float* __restrict__ ybar,
                            const float* __restrict__ SE, const float* __restrict__ SX,
                            const float* __restrict__ urb, const float* __restrict__ red_w,
                            float* __restrict__ scores)
{
    int wv = threadIdx.x >> 6, lane = threadIdx.x & 63;
    int m = blockIdx.x * 4 + wv;
    int b = m >> 10;
    const ushort* xe = G3 + (size_t)m * NCAT + DDIM;
    const float4* yb = (const float4*)(ybar + b * DDIM);
    float s = 0.f;
#pragma unroll
    for (int c0 = 0; c0 < 3; ++c0) {
        int c = lane + c0 * 64;
        short4v v = *(const short4v*)(xe + c * 4);
        float4 yv = yb[c];
        s += b2f((ushort)v[0]) * yv.x + b2f((ushort)v[1]) * yv.y
           + b2f((ushort)v[2]) * yv.z + b2f((ushort)v[3]) * yv.w;
    }
#pragma unroll
    for (int off = 32; off; off >>= 1) s += __shfl_xor(s, off, 64);
    if (lane == 0) {
        float rnx = 1.f / fmaxf(sqrtf(SX[m]), 1e-12f);
        scores[m] = red_w[0] * (SE[m] + urb[0]) + red_w[1] * (rnx * s);
    }
}

// ---------------- out (with inline softmax): grid (B, 32) ----------------
// Each block recomputes batch-b softmax stats from scores (4 KB, L2-hit), then
// accumulates its 32-t chunk of out[b,:] = sum_t softmax(scores)[t] * u[b,t,:].
__global__ void out_sm_k(const ushort* __restrict__ U16, const float* __restrict__ scores,
                         float* __restrict__ out)
{
    int b = blockIdx.x, t0 = blockIdx.y * 32;
    int tid = threadIdx.x;
    int lane = tid & 63, wv = tid >> 6;
    __shared__ float red[8];
    __shared__ float sw[32];

    // block-wide softmax stats over scores[b, 0..1023]
    float v[4];
    float lm = -1e30f;
#pragma unroll
    for (int i = 0; i < 4; ++i) {
        v[i] = scores[b * TSEQ + i * 256 + tid];
        lm = fmaxf(lm, v[i]);
    }
#pragma unroll
    for (int off = 32; off; off >>= 1) lm = fmaxf(lm, __shfl_xor(lm, off, 64));
    if (lane == 0) red[wv] = lm;
    __syncthreads();
    float smax = fmaxf(fmaxf(red[0], red[1]), fmaxf(red[2], red[3]));
    float ls = 0.f;
#pragma unroll
    for (int i = 0; i < 4; ++i) ls += expf(v[i] - smax);
#pragma unroll
    for (int off = 32; off; off >>= 1) ls += __shfl_xor(ls, off, 64);
    if (lane == 0) red[4 + wv] = ls;
    __syncthreads();
    float inv = 1.f / (red[4] + red[5] + red[6] + red[7]);

    if (tid < 32) sw[tid] = expf(scores[b * TSEQ + t0 + tid] - smax) * inv;
    __syncthreads();

    float a0 = 0.f, a1 = 0.f, a2 = 0.f;
#pragma unroll 8
    for (int t = 0; t < 32; ++t) {
        const ushort* row = U16 + (size_t)(b * TSEQ + t0 + t) * DDIM;
        float w = sw[t];
        a0 += b2f(row[tid])       * w;
        a1 += b2f(row[tid + 256]) * w;
        a2 += b2f(row[tid + 512]) * w;
    }
    atomicAdd(&out[b * DDIM + tid],       a0);
    atomicAdd(&out[b * DDIM + tid + 256], a1);
    atomicAdd(&out[b * DDIM + tid + 512], a2);
}

// ---------------- workspace layout (bytes) ----------------
// G3 (e|xe|ye bf16, 151 MB) aliases the X16+H16 region (dead after GEMM2).
static const size_t O_X16   = 0;            // 32768*1536*2 = 100663296
static const size_t O_H16   = 100663296;    // 100663296
static const size_t O_G3    = 0;            // 150994944 (alias)
static const size_t O_U16   = 201326592;    // 50331648
static const size_t O_W1    = 251658240;    // 4718592
static const size_t O_W2    = 256376832;    // 2359296
static const size_t O_W3    = 258736128;    // 3538944
static const size_t O_B3    = 262275072;    // 9216
static const size_t O_SE    = 262284288;    // 131072  (SE/SX/SY contiguous)
static const size_t O_SX    = 262415360;    // 131072
static const size_t O_SY    = 262546432;    // 131072
static const size_t O_SCORE = 262677504;    // 131072
static const size_t O_YBAR  = 262939648;    // 98304
// total: 263037952 bytes (~263 MB)

extern "C" void kernel_launch(void* const* d_in, const int* in_sizes, int n_in,
                              void* d_out, int out_size, void* d_ws, size_t ws_size,
                              hipStream_t stream)
{
    const float* x        = (const float*)d_in[0];
    const float* fc1_w    = (const float*)d_in[1];
    const float* fc1_b    = (const float*)d_in[2];
    const float* fc2_w    = (const float*)d_in[3];
    const float* fc2_b    = (const float*)d_in[4];
    const float* un_emb_w = (const float*)d_in[5];
    const float* un_emb_b = (const float*)d_in[6];
    const float* un_red_w = (const float*)d_in[7];
    const float* un_red_b = (const float*)d_in[8];
    const float* pw_x_w   = (const float*)d_in[9];
    const float* pw_x_b   = (const float*)d_in[10];
    const float* pw_y_w   = (const float*)d_in[11];
    const float* pw_y_b   = (const float*)d_in[12];
    const float* red_w    = (const float*)d_in[13];

    char* ws = (char*)d_ws;
    ushort* X16 = (ushort*)(ws + O_X16);
    ushort* H16 = (ushort*)(ws + O_H16);
    ushort* G3  = (ushort*)(ws + O_G3);
    ushort* U16 = (ushort*)(ws + O_U16);
    ushort* W1  = (ushort*)(ws + O_W1);
    ushort* W2  = (ushort*)(ws + O_W2);
    ushort* W3  = (ushort*)(ws + O_W3);
    float*  B3  = (float*)(ws + O_B3);
    float*  SE  = (float*)(ws + O_SE);
    float*  SX  = (float*)(ws + O_SX);
    float*  SY  = (float*)(ws + O_SY);
    float*  SCORES = (float*)(ws + O_SCORE);
    float*  YBAR = (float*)(ws + O_YBAR);

    // --- one conversion/zeroing pass ---
    cvt_all<<<54483, 256, 0, stream>>>(x, fc1_w, fc2_w, un_emb_w, pw_x_w, pw_y_w,
                                       un_emb_b, pw_x_b, pw_y_b,
                                       X16, W1, W2, W3, B3, YBAR, (float*)d_out, SE);

    // --- GEMM chain (1-D grid, XCD-pinned swizzle inside kernel) ---
    gemm_bt<<<(MROWS / 128) * (INDIM / 128), 256, 0, stream>>>(
        X16, W1, fc1_b, H16, MROWS, INDIM, INDIM, INDIM,
        nullptr, nullptr, nullptr, nullptr);
    gemm_bt<<<(MROWS / 128) * (DDIM / 128), 256, 0, stream>>>(
        H16, W2, fc2_b, U16, MROWS, DDIM, INDIM, 0,
        nullptr, nullptr, nullptr, nullptr);
    gemm_bt<<<(MROWS / 128) * (NCAT / 128), 256, 0, stream>>>(
        U16, W3, B3, G3, MROWS, NCAT, DDIM, DDIM,
        un_red_w, SE, SX, SY);

    // --- tail: ybar -> scores -> out(+softmax), independent small launches ---
    ybar_k<<<dim3(BBATCH, 32), 256, 0, stream>>>(G3, SY, YBAR);
    pw_scores_k<<<MROWS / 4, 256, 0, stream>>>(G3, YBAR, SE, SX, un_red_b, red_w, SCORES);
    out_sm_k<<<dim3(BBATCH, 32), 256, 0, stream>>>(U16, SCORES, (float*)d_out);
}